// Round 5
// baseline (440.646 us; speedup 1.0000x reference)
//
#include <hip/hip_runtime.h>

// Problem: out[b,t,o] = sum_i x[b,t,i] * K[i,o], with K = eye(256)[perm]
// (a permutation matrix). So out[row, o] = x[row, inv_perm[o]] -- a pure
// per-row channel gather. Memory-bound: 537 MB total traffic, ~85 us floor.

#define CCH 256                   // channels
#define NROWS (16 * 16384)        // B*T = 262144
#define ROWS_PER_ITER 4           // 4 rows * 1 KB = 4 KB LDS per iteration

// ---- Prep: derive the permutation (idx) and its weight (val) from K ----
// One block, 256 threads; thread o scans column o. Tiny (256 KB read).
__global__ void build_perm_kernel(const float* __restrict__ K,
                                  int* __restrict__ idx,
                                  float* __restrict__ val) {
    const int o = threadIdx.x;
    float best = -1.0f;
    int bi = 0;
    for (int i = 0; i < CCH; ++i) {
        float a = fabsf(K[i * CCH + o]);
        if (a > best) { best = a; bi = i; }
    }
    idx[o] = bi;
    val[o] = K[bi * CCH + o];   // == 1.0f for a permutation matrix
}

// ---- Main: coalesced float4 load -> LDS -> permuted read -> float4 store ----
__global__ __launch_bounds__(256) void permute_rows_kernel(
        const float4* __restrict__ x4,
        float4* __restrict__ out4,
        const int* __restrict__ idx,
        const float* __restrict__ val) {
    __shared__ float lds[ROWS_PER_ITER * CCH];   // 4 KB

    const int t  = threadIdx.x;
    const int r  = t >> 6;           // local row 0..3 (64 threads per row)
    const int o4 = (t & 63) * 4;     // this thread's 4 output channels

    // Per-thread constants: gather indices + weights (registers, loaded once).
    const int   i0 = idx[o4 + 0], i1 = idx[o4 + 1],
                i2 = idx[o4 + 2], i3 = idx[o4 + 3];
    const float v0 = val[o4 + 0], v1 = val[o4 + 1],
                v2 = val[o4 + 2], v3 = val[o4 + 3];

    const int nchunks = NROWS / ROWS_PER_ITER;   // 65536 chunks of 4 rows
    const int f4_per_chunk = ROWS_PER_ITER * CCH / 4;  // 256 float4

    for (int chunk = blockIdx.x; chunk < nchunks; chunk += gridDim.x) {
        const long base = (long)chunk * f4_per_chunk;

        // Coalesced 16B/lane global load, linear LDS store.
        float4 v = x4[base + t];
        reinterpret_cast<float4*>(lds)[t] = v;
        __syncthreads();

        // Permuted LDS gather (4B reads; random perm ~2-way conflicts = free),
        // coalesced 16B/lane global store.
        const float* row = &lds[r * CCH];
        float4 o;
        o.x = row[i0] * v0;
        o.y = row[i1] * v1;
        o.z = row[i2] * v2;
        o.w = row[i3] * v3;
        out4[base + t] = o;
        __syncthreads();   // protect LDS before next iteration overwrites
    }
}

extern "C" void kernel_launch(void* const* d_in, const int* in_sizes, int n_in,
                              void* d_out, int out_size, void* d_ws, size_t ws_size,
                              hipStream_t stream) {
    const float* x = (const float*)d_in[0];        // [B,T,C] fp32
    const float* K = (const float*)d_in[1];        // [C,C]   fp32
    float* out = (float*)d_out;

    int*   idx = (int*)d_ws;                        // 256 ints
    float* val = (float*)((char*)d_ws + CCH * sizeof(int));  // 256 floats

    build_perm_kernel<<<1, CCH, 0, stream>>>(K, idx, val);

    const int grid = 2048;   // 8 blocks/CU, grid-stride over 65536 chunks
    permute_rows_kernel<<<grid, 256, 0, stream>>>(
        (const float4*)x, (float4*)out, idx, val);
}